// Round 1
// 288.853 us; speedup vs baseline: 1.0038x; 1.0038x over previous
//
#include <hip/hip_runtime.h>
#include <hip/hip_bf16.h>
#include <cstdint>

typedef __attribute__((ext_vector_type(8))) short short8;
typedef __attribute__((ext_vector_type(4))) short short4_;
typedef __attribute__((ext_vector_type(4))) float float4_;

#define MFMA16(a,b,c)  __builtin_amdgcn_mfma_f32_16x16x32_bf16(a,b,c,0,0,0)
#define MFMA16K16(a,b,c) __builtin_amdgcn_mfma_f32_16x16x16bf16_1k(a,b,c,0,0,0)
#define EXP2(x) __builtin_amdgcn_exp2f(x)

// fast bf16 RNE: bit-identical to __float2bfloat16 for all non-NaN inputs.
__device__ __forceinline__ short f2bs(float f) {
    union { float f; uint32_t u; } c;
    c.f = f;
    c.u += 0x7FFF + ((c.u >> 16) & 1);
    return (short)(c.u >> 16);
}
__device__ __forceinline__ float s2f(short s) {
    union { uint32_t u; float f; } c;
    c.u = ((uint32_t)(uint16_t)s) << 16;
    return c.f;
}

static const int EMB = 256;
static const int SEQ = 4096;   // 64*64 spatial
static const int TOK = 16384;  // BS * SEQ

// Attention scale folded into wq/bq: (1/8) * log2(e) -> softmax in exp2 domain.
#define QSCALE 0.18033688011112042f

// ---------------------------------------------------------------- repack ----
__global__ __launch_bounds__(256) void repack_kernel(
    const float* wq, const float* wk, const float* wv,
    const float* wo, const float* w1, const float* w2,
    short* wqT, short* wkT, short* wvT, short* woT, short* w1T, short* w2T)
{
    int idx = blockIdx.x * 256 + threadIdx.x;
    if (idx < 3 * 4096) {
        int m = idx / 4096, r = idx % 4096;
        int n = r / 64, k = r % 64;
        const float* src = (m == 0) ? wq : (m == 1) ? wk : wv;
        short* dst = (m == 0) ? wqT : (m == 1) ? wkT : wvT;
        float v = src[k * 64 + n];
        if (m == 0) v *= QSCALE;
        dst[n * 64 + k] = f2bs(v);
    } else {
        int idx2 = idx - 3 * 4096;
        if (idx2 < 3 * 65536) {
            int m = idx2 / 65536, r = idx2 % 65536;
            int n = r / 256, k = r % 256;
            const float* src = (m == 0) ? wo : (m == 1) ? w1 : w2;
            short* dst = (m == 0) ? woT : (m == 1) ? w1T : w2T;
            dst[n * 256 + k] = f2bs(src[k * 256 + n]);
        }
    }
}

// ------------------------------------------------------------------- ln1 ----
// (verbatim — passing)
__global__ __launch_bounds__(64) void ln1_kernel(
    const float* x, const float* g, const float* bta,
    short* xn, short* xt)
{
    int t = blockIdx.x * 64 + threadIdx.x;
    int b = t >> 12, sp = t & 4095;
    const float* xb = x + (size_t)b * EMB * SEQ + sp;
    float sum = 0.f, ss = 0.f;
#pragma unroll 32
    for (int c = 0; c < 256; c++) {
        float v = xb[(size_t)c * SEQ];
        sum += v; ss += v * v;
    }
    float mu = sum * (1.f / 256.f);
    float var = ss * (1.f / 256.f) - mu * mu;
    float rs = rsqrtf(var + 1e-5f);
    short* xnr = xn + (size_t)t * 256;
    short* xtr = xt + (size_t)t * 256;
#pragma unroll 8
    for (int c = 0; c < 256; c += 4) {
        short4_ ra, na;
#pragma unroll
        for (int j = 0; j < 4; j++) {
            float v = xb[(size_t)(c + j) * SEQ];
            ra[j] = f2bs(v);
            na[j] = f2bs((v - mu) * rs * g[c + j] + bta[c + j]);
        }
        *(short4_*)(xtr + c) = ra;
        *(short4_*)(xnr + c) = na;
    }
}

// ------------------------------------------------------------------- qkv ----
// (verbatim — passing)
__global__ __launch_bounds__(256) void qkv_kernel(
    const short* xn, const short* wqT, const short* wkT, const short* wvT,
    const float* bq, const float* bk, const float* bv,
    short* qo, short* ko, short* vto)
{
    int tid = threadIdx.x;
    int w = tid >> 6, lane = tid & 63, quad = lane >> 4, l15 = lane & 15;
    int m0 = blockIdx.x * 64 + w * 16;
    int row = m0 + l15;
    int bb = row >> 12;
    int s0 = (m0 & 4095) + quad * 4;

    short8 a0[4], a1[4];
#pragma unroll
    for (int h = 0; h < 4; h++) {
        a0[h] = *(const short8*)(xn + (size_t)row * 256 + h * 64 + quad * 8);
        a1[h] = *(const short8*)(xn + (size_t)row * 256 + h * 64 + 32 + quad * 8);
    }

#pragma unroll
    for (int p = 0; p < 3; p++) {
        const short* WT = (p == 0) ? wqT : (p == 1) ? wkT : wvT;
        const float* bias = (p == 0) ? bq : (p == 1) ? bk : bv;
        float bscale = (p == 0) ? QSCALE : 1.f;
#pragma unroll
        for (int nb = 0; nb < 4; nb++) {
            int col = nb * 16 + l15;
            short8 b0 = *(const short8*)(WT + col * 64 + quad * 8);
            short8 b1 = *(const short8*)(WT + col * 64 + 32 + quad * 8);
            float bvv = bias[col] * bscale;
#pragma unroll
            for (int h = 0; h < 4; h++) {
                float4_ acc = {bvv, bvv, bvv, bvv};
                acc = MFMA16(a0[h], b0, acc);
                acc = MFMA16(a1[h], b1, acc);
                size_t headbase = (size_t)(bb * 4 + h) * SEQ;
                if (p < 2) {
                    short* dst = (p == 0) ? qo : ko;
#pragma unroll
                    for (int r = 0; r < 4; r++)
                        dst[(headbase + s0 + r) * 64 + col] = f2bs(acc[r]);
                } else {
                    short4_ pk;
#pragma unroll
                    for (int r = 0; r < 4; r++) pk[r] = f2bs(acc[r]);
                    *(short4_*)(vto + ((size_t)(bb * 4 + h) * 64 + col) * SEQ + s0) = pk;
                }
            }
        }
    }
}

// ----------------------------------------------------------------- flash ----
// v8: T14 async-STAGE split + cvt_pk packing.
//  - K/V tile kt+1 is prefetched into registers DURING compute of tile kt;
//    the loads stay in flight across the pre-compute barrier, which is now a
//    raw s_barrier + lgkmcnt(0) (NO vmcnt drain -- __syncthreads would kill
//    the pipeline by draining vmcnt(0) before s_barrier).
//  - Loop-top barrier stays __syncthreads(): its vmcnt(0) is ~free (prefetch
//    is a full compute-phase old) and it safely orders LDS reuse.
//  - P->bf16 packing via v_cvt_pk_bf16_f32 (HW RNE, bit-compatible with
//    f2bs): 2 scores/instr instead of ~3-4 VALU ops/score.
__global__ __launch_bounds__(256, 4) void flash_kernel(
    const short* q, const short* k, const short* vt,
    short* O0, short* O1, float* l0, float* l1)
{
    __shared__ short K_lds[64 * 64];
    __shared__ short V_lds[64 * 64];

    int tid = threadIdx.x;
    int w = tid >> 6, lane = tid & 63, quad = lane >> 4, l15 = lane & 15;
    int qt = blockIdx.x, bh = blockIdx.y, grp = blockIdx.z;
    int span = 64 / gridDim.z;              // K-tiles per block

    const short* qb = q + (size_t)bh * SEQ * 64;
    const short* kb = k + (size_t)bh * SEQ * 64 + (size_t)grp * span * 64 * 64;
    const short* vb = vt + (size_t)bh * 64 * SEQ + grp * span * 64;

    int qrow0 = qt * 128 + w * 32 + l15;
    int qrow1 = qrow0 + 16;
    short8 qA0 = *(const short8*)(qb + (size_t)qrow0 * 64 + quad * 8);
    short8 qA1 = *(const short8*)(qb + (size_t)qrow0 * 64 + 32 + quad * 8);
    short8 qB0 = *(const short8*)(qb + (size_t)qrow1 * 64 + quad * 8);
    short8 qB1 = *(const short8*)(qb + (size_t)qrow1 * 64 + 32 + quad * 8);

    float4_ oacc0[4], oacc1[4];   // O^T[d = md*16 + quad*4 + r][query = l15]
#pragma unroll
    for (int md = 0; md < 4; md++) {
        oacc0[md] = {0.f, 0.f, 0.f, 0.f};
        oacc1[md] = {0.f, 0.f, 0.f, 0.f};
    }
    float li0 = 0.f, li1 = 0.f;

    int srow = tid >> 2;          // 0..63
    int sr7 = srow & 7;
    int c0 = tid & 3;             // chunk (16B units)
    int l7 = l15 & 7;

    int dcA = (c0 ^ sr7) << 3;
    int dcB = ((c0 + 4) ^ sr7) << 3;

    // prologue: stage tile 0 into registers
    short8 kr0 = *(const short8*)(kb + (size_t)srow * 64 + c0 * 8);
    short8 kr1 = *(const short8*)(kb + (size_t)srow * 64 + (c0 + 4) * 8);
    short8 vr0 = *(const short8*)(vb + (size_t)srow * SEQ + c0 * 8);
    short8 vr1 = *(const short8*)(vb + (size_t)srow * SEQ + (c0 + 4) * 8);

    for (int kt = 0; kt < span; kt++) {
        __syncthreads();          // prev-tile LDS reads done; vmcnt drain ~free
        *(short8*)&K_lds[srow * 64 + dcA] = kr0;
        *(short8*)&K_lds[srow * 64 + dcB] = kr1;
        *(short8*)&V_lds[srow * 64 + dcA] = vr0;
        *(short8*)&V_lds[srow * 64 + dcB] = vr1;
        if (kt + 1 < span) {      // prefetch kt+1: stays in flight across barrier
            kr0 = *(const short8*)(kb + (size_t)((kt + 1) * 64 + srow) * 64 + c0 * 8);
            kr1 = *(const short8*)(kb + (size_t)((kt + 1) * 64 + srow) * 64 + (c0 + 4) * 8);
            vr0 = *(const short8*)(vb + (size_t)srow * SEQ + (kt + 1) * 64 + c0 * 8);
            vr1 = *(const short8*)(vb + (size_t)srow * SEQ + (kt + 1) * 64 + (c0 + 4) * 8);
        }
        asm volatile("s_waitcnt lgkmcnt(0)" ::: "memory");  // my ds_writes done
        __builtin_amdgcn_s_barrier();                       // no vmcnt(0) drain
        asm volatile("" ::: "memory");

        float4_ s0[4], s1[4];
#pragma unroll
        for (int nb = 0; nb < 4; nb++) {
            short8 k0 = *(const short8*)&K_lds[(nb * 16 + l15) * 64 + ((quad ^ l7) << 3)];
            short8 k1 = *(const short8*)&K_lds[(nb * 16 + l15) * 64 + (((quad + 4) ^ l7) << 3)];
            float4_ a = {0.f, 0.f, 0.f, 0.f};
            a = MFMA16(k0, qA0, a);
            a = MFMA16(k1, qA1, a);
            s0[nb] = a;
            float4_ b = {0.f, 0.f, 0.f, 0.f};
            b = MFMA16(k0, qB0, b);
            b = MFMA16(k1, qB1, b);
            s1[nb] = b;
        }

        short4_ pf0[4], pf1[4];
#pragma unroll
        for (int nb = 0; nb < 4; nb++) {
            float p00 = EXP2(s0[nb][0]), p01 = EXP2(s0[nb][1]);
            float p02 = EXP2(s0[nb][2]), p03 = EXP2(s0[nb][3]);
            li0 += (p00 + p01) + (p02 + p03);
            float p10 = EXP2(s1[nb][0]), p11 = EXP2(s1[nb][1]);
            float p12 = EXP2(s1[nb][2]), p13 = EXP2(s1[nb][3]);
            li1 += (p10 + p11) + (p12 + p13);
            union { short4_ s; uint32_t u[2]; } pa, pb;
            asm("v_cvt_pk_bf16_f32 %0, %1, %2" : "=v"(pa.u[0]) : "v"(p00), "v"(p01));
            asm("v_cvt_pk_bf16_f32 %0, %1, %2" : "=v"(pa.u[1]) : "v"(p02), "v"(p03));
            asm("v_cvt_pk_bf16_f32 %0, %1, %2" : "=v"(pb.u[0]) : "v"(p10), "v"(p11));
            asm("v_cvt_pk_bf16_f32 %0, %1, %2" : "=v"(pb.u[1]) : "v"(p12), "v"(p13));
            pf0[nb] = pa.s;
            pf1[nb] = pb.s;
        }

#pragma unroll
        for (int md = 0; md < 4; md++)
#pragma unroll
            for (int nb = 0; nb < 4; nb++) {
                int c = nb * 2 + (quad >> 1);
                short4_ vf = *(const short4_*)&V_lds[(md * 16 + l15) * 64 +
                                                     ((c ^ l7) << 3) + ((quad & 1) << 2)];
                oacc0[md] = MFMA16K16(vf, pf0[nb], oacc0[md]);
                oacc1[md] = MFMA16K16(vf, pf1[nb], oacc1[md]);
            }
    }

    li0 += __shfl_xor(li0, 16);
    li0 += __shfl_xor(li0, 32);
    li1 += __shfl_xor(li1, 16);
    li1 += __shfl_xor(li1, 32);

    short* Op = grp ? O1 : O0;
    float* lp = grp ? l1 : l0;
    if (quad == 0) {
        lp[bh * 4096 + qrow0] = li0;
        lp[bh * 4096 + qrow1] = li1;
    }

    size_t ob0 = ((size_t)bh * 4096 + qrow0) * 64;
    size_t ob1 = ((size_t)bh * 4096 + qrow1) * 64;
#pragma unroll
    for (int md = 0; md < 4; md++) {
        short4_ pk0, pk1;
#pragma unroll
        for (int r = 0; r < 4; r++) {
            pk0[r] = f2bs(oacc0[md][r]);
            pk1[r] = f2bs(oacc1[md][r]);
        }
        *(short4_*)(Op + ob0 + md * 16 + quad * 4) = pk0;
        *(short4_*)(Op + ob1 + md * 16 + quad * 4) = pk1;
    }
}

// --------------------------------------------------------------- combine ----
// v2: OUT-OF-PLACE (Oout in ws) so the fused MLP kernel can write all of
// d_out without racing O0 reads. out = (O0 [+ O1]) / (l0 [+ l1]).
__global__ __launch_bounds__(256) void combine_kernel(
    const short* O0, const short* O1, const float* l0, const float* l1,
    short* Oout, int two)
{
    int g = blockIdx.x * 256 + threadIdx.x;     // short4 units, 1048576 total
    int qi = g >> 4;
    short4_ a = *(const short4_*)(O0 + (size_t)g * 4);
    float l = l0[qi];
    float4_ acc = {s2f(a[0]), s2f(a[1]), s2f(a[2]), s2f(a[3])};
    if (two) {
        short4_ b = *(const short4_*)(O1 + (size_t)g * 4);
        l += l1[qi];
#pragma unroll
        for (int j = 0; j < 4; j++) acc[j] += s2f(b[j]);
    }
    float inv = 1.f / l;
    short4_ pk;
#pragma unroll
    for (int j = 0; j < 4; j++) pk[j] = f2bs(acc[j] * inv);
    *(short4_*)(Oout + (size_t)g * 4) = pk;
}

// ------------------------------------------------------------------- mlp ----
// Fused back half: (O@woT + bo + xt) -> av -> LN2 -> xn2 -> (@w1T + b1) ->
// GELU -> ff -> (@w2T + b2 + av) -> fp32 transpose-store to [b][c][sp].
// Block = 16 tokens x 256 cols (4 waves x 64-col slices); av/xn2/ff live in
// LDS tiles (pitch 264: rows 16B-aligned, b128 reads 2-way max).
// Replaces gemm0 + ln2 + gemm1 + gemm2 (saves 48 MB HBM round-trips + 3
// launches). fp32 transpose buffer aliases av|x2 after the final sync.
__global__ __launch_bounds__(256) void mlp_kernel(
    const short* O,                     // normalized attn out, (bh,q,d)
    const short* woT, const short* w1T, const short* w2T,
    const float* bo, const float* b1, const float* b2,
    const float* g2, const float* be2,
    const short* xt, float* outf)
{
    __shared__ __align__(16) char smem[3 * 8448 + 128];
    short* av = (short*)smem;                   // [16][264] bf16
    short* x2 = (short*)(smem + 8448);          // [16][264] bf16
    short* ff = (short*)(smem + 16896);         // [16][264] bf16
    float* stats = (float*)(smem + 25344);      // mu[16], rs[16]
    float* T = (float*)smem;                    // alias av|x2 (16.6 KB <= 16.9)

    int tid = threadIdx.x;
    int w = tid >> 6, lane = tid & 63, quad = lane >> 4, l15 = lane & 15;
    int m0 = blockIdx.x * 16;
    int n0 = w * 64;
    int arow = m0 + l15;
    int bbA = arow >> 12, spA = arow & 4095;

    // ---- stage A: attention out-proj + xt residual -> av (LDS bf16) ----
    float4_ acc[4];
#pragma unroll
    for (int nb = 0; nb < 4; nb++) {
        float bvv = bo[n0 + nb * 16 + l15];
        acc[nb] = {bvv, bvv, bvv, bvv};
    }
    for (int kc = 0; kc < 8; kc++) {
        int h = kc >> 1;
        int off = (kc & 1) * 32 + quad * 8;
        short8 a = *(const short8*)(O + ((size_t)(bbA * 4 + h) * 4096 + spA) * 64 + off);
#pragma unroll
        for (int nb = 0; nb < 4; nb++) {
            short8 b = *(const short8*)(woT + (size_t)(n0 + nb * 16 + l15) * 256 + kc * 32 + quad * 8);
            acc[nb] = MFMA16(a, b, acc[nb]);
        }
    }
#pragma unroll
    for (int nb = 0; nb < 4; nb++) {
        int col = n0 + nb * 16 + l15;
#pragma unroll
        for (int r = 0; r < 4; r++) {
            size_t t = (size_t)m0 + quad * 4 + r;
            av[(quad * 4 + r) * 264 + col] = f2bs(acc[nb][r] + s2f(xt[t * 256 + col]));
        }
    }
    __syncthreads();

    // ---- stage B: LN2 stats (16 threads per row, each sums 16 cols) ----
    {
        int row = tid >> 4, sub = tid & 15;
        float sum = 0.f, ss = 0.f;
        short8 v0 = *(const short8*)&av[row * 264 + sub * 16];
        short8 v1 = *(const short8*)&av[row * 264 + sub * 16 + 8];
#pragma unroll
        for (int j = 0; j < 8; j++) {
            float a = s2f(v0[j]), b = s2f(v1[j]);
            sum += a + b; ss += a * a + b * b;
        }
#pragma unroll
        for (int off = 1; off < 16; off <<= 1) {
            sum += __shfl_xor(sum, off);
            ss += __shfl_xor(ss, off);
        }
        if (sub == 0) {
            float mu = sum * (1.f / 256.f);
            float var = ss * (1.f / 256.f) - mu * mu;
            stats[row] = mu;
            stats[16 + row] = rsqrtf(var + 1e-5f);
        }
    }
    __syncthreads();

    // ---- stage C: xn2 = (av - mu) * rs * g2 + be2 (LDS bf16) ----
    {
        int row = tid >> 4, sub = tid & 15;
        float mu = stats[row], rs = stats[16 + row];
#pragma unroll
        for (int j = 0; j < 16; j += 4) {
            int c = sub * 16 + j;
            short4_ rv = *(const short4_*)&av[row * 264 + c];
            short4_ pk;
#pragma unroll
            for (int i = 0; i < 4; i++)
                pk[i] = f2bs((s2f(rv[i]) - mu) * rs * g2[c + i] + be2[c + i]);
            *(short4_*)&x2[row * 264 + c] = pk;
        }
    }
    __syncthreads();

    // ---- stage D: gemm1 + exact GELU -> ff (LDS bf16) ----
#pragma unroll
    for (int nb = 0; nb < 4; nb++) {
        float bvv = b1[n0 + nb * 16 + l15];
        acc[nb] = {bvv, bvv, bvv, bvv};
    }
    for (int kc = 0; kc < 8; kc++) {
        short8 a = *(const short8*)&x2[l15 * 264 + kc * 32 + quad * 8];
#pragma unroll
        for (int nb = 0; nb < 4; nb++) {
            short8 b = *(const short8*)(w1T + (size_t)(n0 + nb * 16 + l15) * 256 + kc * 32 + quad * 8);
            acc[nb] = MFMA16(a, b, acc[nb]);
        }
    }
#pragma unroll
    for (int nb = 0; nb < 4; nb++) {
        int col = n0 + nb * 16 + l15;
#pragma unroll
        for (int r = 0; r < 4; r++) {
            float v = acc[nb][r];
            v = 0.5f * v * (1.f + erff(v * 0.70710678118f));
            ff[(quad * 4 + r) * 264 + col] = f2bs(v);
        }
    }
    __syncthreads();

    // ---- stage E: gemm2 + av residual ----
#pragma unroll
    for (int nb = 0; nb < 4; nb++) {
        float bvv = b2[n0 + nb * 16 + l15];
        acc[nb] = {bvv, bvv, bvv, bvv};
    }
    for (int kc = 0; kc < 8; kc++) {
        short8 a = *(const short8*)&ff[l15 * 264 + kc * 32 + quad * 8];
#pragma unroll
        for (int nb = 0; nb < 4; nb++) {
            short8 b = *(const short8*)(w2T + (size_t)(n0 + nb * 16 + l15) * 256 + kc * 32 + quad * 8);
            acc[nb] = MFMA16(a, b, acc[nb]);
        }
    }
    float vout[4][4];
#pragma unroll
    for (int nb = 0; nb < 4; nb++) {
        int col = n0 + nb * 16 + l15;
#pragma unroll
        for (int r = 0; r < 4; r++)
            vout[nb][r] = acc[nb][r] + s2f(av[(quad * 4 + r) * 264 + col]);
    }
    __syncthreads();   // all reads of av/x2/ff complete before T alias writes

    // wave-private fp32 transpose -> coalesced [b][c][sp] stores
    float* tw = T + w * 1040;
#pragma unroll
    for (int nb = 0; nb < 4; nb++)
#pragma unroll
        for (int r = 0; r < 4; r++)
            tw[(quad * 4 + r) * 65 + nb * 16 + l15] = vout[nb][r];

    int bb = m0 >> 12;
    int spb = m0 & 4095;
    float* dst = outf + ((size_t)bb * 256 + n0 + lane) * SEQ + spb;
#pragma unroll
    for (int j = 0; j < 16; j += 4) {
        float4_ pk = {tw[(j + 0) * 65 + lane], tw[(j + 1) * 65 + lane],
                      tw[(j + 2) * 65 + lane], tw[(j + 3) * 65 + lane]};
        *(float4_*)(dst + j) = pk;
    }
}

// ---------------------------------------------------------------- launch ----
// d_out: lower 8 MB q; upper 8 MB xn -> O0 partial. combine writes normalized
// O into vtb (ws, dead after flash) so mlp_kernel can write ALL of d_out with
// every input in ws. ws peak = 33 MB (proven available: nz=2 active r8-r11).
extern "C" void kernel_launch(void* const* d_in, const int* in_sizes, int n_in,
                              void* d_out, int out_size, void* d_ws, size_t ws_size,
                              hipStream_t stream)
{
    const float* x     = (const float*)d_in[0];
    const float* ln1_g = (const float*)d_in[1];
    const float* ln1_b = (const float*)d_in[2];
    const float* wq    = (const float*)d_in[3];
    const float* bq    = (const float*)d_in[4];
    const float* wk    = (const float*)d_in[5];
    const float* bk    = (const float*)d_in[6];
    const float* wv    = (const float*)d_in[7];
    const float* bv    = (const float*)d_in[8];
    const float* wo    = (const float*)d_in[9];
    const float* bo    = (const float*)d_in[10];
    const float* ln2_g = (const float*)d_in[11];
    const float* ln2_b = (const float*)d_in[12];
    const float* w1    = (const float*)d_in[13];
    const float* b1    = (const float*)d_in[14];
    const float* w2    = (const float*)d_in[15];
    const float* b2    = (const float*)d_in[16];

    char* ws = (char*)d_ws;
    const size_t SZ_BF = (size_t)TOK * 256 * 2;  // 8 MB

    short* wqT = (short*)(ws + 0);
    short* wkT = (short*)(ws + 8192);
    short* wvT = (short*)(ws + 16384);
    short* woT = (short*)(ws + 24576);
    short* w1T = (short*)(ws + 155648);
    short* w2T = (short*)(ws + 286720);
    char* base = ws + 524288;

    short* xt  = (short*)(base);
    short* kbuf= (short*)(base + SZ_BF);
    short* vtb = (short*)(base + 2 * SZ_BF);
    float* l0  = (float*)(base + 3 * SZ_BF);             // 256 KB
    float* l1  = (float*)(base + 3 * SZ_BF + 262144);    // 256 KB
    short* O1  = (short*)(base + 3 * SZ_BF + 524288);    // 8 MB (split only)

    const size_t NEED_SPLIT = 524288 + 3 * SZ_BF + 524288 + SZ_BF;
    int nz = (ws_size >= NEED_SPLIT) ? 2 : 1;

    short* qb  = (short*)d_out;                      // lower 8 MB
    short* xn  = (short*)((char*)d_out + SZ_BF);     // upper 8 MB
    short* O0  = xn;                                 // partial O over xn
    short* Onrm= vtb;                                // normalized O (ws, over v)

    repack_kernel<<<816, 256, 0, stream>>>(wq, wk, wv, wo, w1, w2,
                                           wqT, wkT, wvT, woT, w1T, w2T);
    ln1_kernel<<<TOK / 64, 64, 0, stream>>>(x, ln1_g, ln1_b, xn, xt);
    qkv_kernel<<<TOK / 64, 256, 0, stream>>>(xn, wqT, wkT, wvT, bq, bk, bv,
                                             qb, kbuf, vtb);
    flash_kernel<<<dim3(32, 16, nz), 256, 0, stream>>>(qb, kbuf, vtb, O0, O1, l0, l1);
    combine_kernel<<<4096, 256, 0, stream>>>(O0, O1, l0, l1, Onrm, nz - 1);
    mlp_kernel<<<TOK / 16, 256, 0, stream>>>(Onrm, woT, w1T, w2T, bo, b1, b2,
                                             ln2_g, ln2_b, xt, (float*)d_out);
}

// Round 2
// 280.256 us; speedup vs baseline: 1.0346x; 1.0307x over previous
//
#include <hip/hip_runtime.h>
#include <hip/hip_bf16.h>
#include <cstdint>

typedef __attribute__((ext_vector_type(8))) short short8;
typedef __attribute__((ext_vector_type(4))) short short4_;
typedef __attribute__((ext_vector_type(4))) float float4_;

#define MFMA16(a,b,c)  __builtin_amdgcn_mfma_f32_16x16x32_bf16(a,b,c,0,0,0)
#define MFMA16K16(a,b,c) __builtin_amdgcn_mfma_f32_16x16x16bf16_1k(a,b,c,0,0,0)
#define EXP2(x) __builtin_amdgcn_exp2f(x)

// fast bf16 RNE: bit-identical to __float2bfloat16 for all non-NaN inputs.
__device__ __forceinline__ short f2bs(float f) {
    union { float f; uint32_t u; } c;
    c.f = f;
    c.u += 0x7FFF + ((c.u >> 16) & 1);
    return (short)(c.u >> 16);
}
__device__ __forceinline__ float s2f(short s) {
    union { uint32_t u; float f; } c;
    c.u = ((uint32_t)(uint16_t)s) << 16;
    return c.f;
}

static const int EMB = 256;
static const int SEQ = 4096;   // 64*64 spatial
static const int TOK = 16384;  // BS * SEQ

// Attention scale folded into wq/bq: (1/8) * log2(e) -> softmax in exp2 domain.
#define QSCALE 0.18033688011112042f

// ---------------------------------------------------------------- repack ----
__global__ __launch_bounds__(256) void repack_kernel(
    const float* wq, const float* wk, const float* wv,
    const float* wo, const float* w1, const float* w2,
    short* wqT, short* wkT, short* wvT, short* woT, short* w1T, short* w2T)
{
    int idx = blockIdx.x * 256 + threadIdx.x;
    if (idx < 3 * 4096) {
        int m = idx / 4096, r = idx % 4096;
        int n = r / 64, k = r % 64;
        const float* src = (m == 0) ? wq : (m == 1) ? wk : wv;
        short* dst = (m == 0) ? wqT : (m == 1) ? wkT : wvT;
        float v = src[k * 64 + n];
        if (m == 0) v *= QSCALE;
        dst[n * 64 + k] = f2bs(v);
    } else {
        int idx2 = idx - 3 * 4096;
        if (idx2 < 3 * 65536) {
            int m = idx2 / 65536, r = idx2 % 65536;
            int n = r / 256, k = r % 256;
            const float* src = (m == 0) ? wo : (m == 1) ? w1 : w2;
            short* dst = (m == 0) ? woT : (m == 1) ? w1T : w2T;
            dst[n * 256 + k] = f2bs(src[k * 256 + n]);
        }
    }
}

// ------------------------------------------------------------------- ln1 ----
// (verbatim — passing)
__global__ __launch_bounds__(64) void ln1_kernel(
    const float* x, const float* g, const float* bta,
    short* xn, short* xt)
{
    int t = blockIdx.x * 64 + threadIdx.x;
    int b = t >> 12, sp = t & 4095;
    const float* xb = x + (size_t)b * EMB * SEQ + sp;
    float sum = 0.f, ss = 0.f;
#pragma unroll 32
    for (int c = 0; c < 256; c++) {
        float v = xb[(size_t)c * SEQ];
        sum += v; ss += v * v;
    }
    float mu = sum * (1.f / 256.f);
    float var = ss * (1.f / 256.f) - mu * mu;
    float rs = rsqrtf(var + 1e-5f);
    short* xnr = xn + (size_t)t * 256;
    short* xtr = xt + (size_t)t * 256;
#pragma unroll 8
    for (int c = 0; c < 256; c += 4) {
        short4_ ra, na;
#pragma unroll
        for (int j = 0; j < 4; j++) {
            float v = xb[(size_t)(c + j) * SEQ];
            ra[j] = f2bs(v);
            na[j] = f2bs((v - mu) * rs * g[c + j] + bta[c + j]);
        }
        *(short4_*)(xtr + c) = ra;
        *(short4_*)(xnr + c) = na;
    }
}

// ------------------------------------------------------------------- qkv ----
// (verbatim — passing)
__global__ __launch_bounds__(256) void qkv_kernel(
    const short* xn, const short* wqT, const short* wkT, const short* wvT,
    const float* bq, const float* bk, const float* bv,
    short* qo, short* ko, short* vto)
{
    int tid = threadIdx.x;
    int w = tid >> 6, lane = tid & 63, quad = lane >> 4, l15 = lane & 15;
    int m0 = blockIdx.x * 64 + w * 16;
    int row = m0 + l15;
    int bb = row >> 12;
    int s0 = (m0 & 4095) + quad * 4;

    short8 a0[4], a1[4];
#pragma unroll
    for (int h = 0; h < 4; h++) {
        a0[h] = *(const short8*)(xn + (size_t)row * 256 + h * 64 + quad * 8);
        a1[h] = *(const short8*)(xn + (size_t)row * 256 + h * 64 + 32 + quad * 8);
    }

#pragma unroll
    for (int p = 0; p < 3; p++) {
        const short* WT = (p == 0) ? wqT : (p == 1) ? wkT : wvT;
        const float* bias = (p == 0) ? bq : (p == 1) ? bk : bv;
        float bscale = (p == 0) ? QSCALE : 1.f;
#pragma unroll
        for (int nb = 0; nb < 4; nb++) {
            int col = nb * 16 + l15;
            short8 b0 = *(const short8*)(WT + col * 64 + quad * 8);
            short8 b1 = *(const short8*)(WT + col * 64 + 32 + quad * 8);
            float bvv = bias[col] * bscale;
#pragma unroll
            for (int h = 0; h < 4; h++) {
                float4_ acc = {bvv, bvv, bvv, bvv};
                acc = MFMA16(a0[h], b0, acc);
                acc = MFMA16(a1[h], b1, acc);
                size_t headbase = (size_t)(bb * 4 + h) * SEQ;
                if (p < 2) {
                    short* dst = (p == 0) ? qo : ko;
#pragma unroll
                    for (int r = 0; r < 4; r++)
                        dst[(headbase + s0 + r) * 64 + col] = f2bs(acc[r]);
                } else {
                    short4_ pk;
#pragma unroll
                    for (int r = 0; r < 4; r++) pk[r] = f2bs(acc[r]);
                    *(short4_*)(vto + ((size_t)(bb * 4 + h) * 64 + col) * SEQ + s0) = pk;
                }
            }
        }
    }
}

// ----------------------------------------------------------------- flash ----
// v9: v8 + register-pressure fix.
//  - amdgpu_waves_per_eu(4,4): grid is 4 blocks/CU (16 waves) regardless, so
//    let regalloc use up to 128 VGPR instead of squeezing to 64 + spilling
//    (v8 showed +10 MB WRITE_SIZE = scratch leak).
//  - exp2/cvt_pk fused into the QK nb-loop: s0/s1 score arrays never live
//    (saves ~24 peak VGPRs); scores die into pf immediately.
//  - T5 setprio(1) around the PV MFMA cluster.
__global__ __attribute__((amdgpu_flat_work_group_size(256, 256),
                          amdgpu_waves_per_eu(4, 4)))
void flash_kernel(
    const short* q, const short* k, const short* vt,
    short* O0, short* O1, float* l0, float* l1)
{
    __shared__ short K_lds[64 * 64];
    __shared__ short V_lds[64 * 64];

    int tid = threadIdx.x;
    int w = tid >> 6, lane = tid & 63, quad = lane >> 4, l15 = lane & 15;
    int qt = blockIdx.x, bh = blockIdx.y, grp = blockIdx.z;
    int span = 64 / gridDim.z;              // K-tiles per block

    const short* qb = q + (size_t)bh * SEQ * 64;
    const short* kb = k + (size_t)bh * SEQ * 64 + (size_t)grp * span * 64 * 64;
    const short* vb = vt + (size_t)bh * 64 * SEQ + grp * span * 64;

    int qrow0 = qt * 128 + w * 32 + l15;
    int qrow1 = qrow0 + 16;
    short8 qA0 = *(const short8*)(qb + (size_t)qrow0 * 64 + quad * 8);
    short8 qA1 = *(const short8*)(qb + (size_t)qrow0 * 64 + 32 + quad * 8);
    short8 qB0 = *(const short8*)(qb + (size_t)qrow1 * 64 + quad * 8);
    short8 qB1 = *(const short8*)(qb + (size_t)qrow1 * 64 + 32 + quad * 8);

    float4_ oacc0[4], oacc1[4];   // O^T[d = md*16 + quad*4 + r][query = l15]
#pragma unroll
    for (int md = 0; md < 4; md++) {
        oacc0[md] = {0.f, 0.f, 0.f, 0.f};
        oacc1[md] = {0.f, 0.f, 0.f, 0.f};
    }
    float li0 = 0.f, li1 = 0.f;

    int srow = tid >> 2;          // 0..63
    int sr7 = srow & 7;
    int c0 = tid & 3;             // chunk (16B units)
    int l7 = l15 & 7;

    int dcA = (c0 ^ sr7) << 3;
    int dcB = ((c0 + 4) ^ sr7) << 3;

    // prologue: stage tile 0 into registers
    short8 kr0 = *(const short8*)(kb + (size_t)srow * 64 + c0 * 8);
    short8 kr1 = *(const short8*)(kb + (size_t)srow * 64 + (c0 + 4) * 8);
    short8 vr0 = *(const short8*)(vb + (size_t)srow * SEQ + c0 * 8);
    short8 vr1 = *(const short8*)(vb + (size_t)srow * SEQ + (c0 + 4) * 8);

    for (int kt = 0; kt < span; kt++) {
        __syncthreads();          // prev-tile LDS reads done; vmcnt drain ~free
        *(short8*)&K_lds[srow * 64 + dcA] = kr0;
        *(short8*)&K_lds[srow * 64 + dcB] = kr1;
        *(short8*)&V_lds[srow * 64 + dcA] = vr0;
        *(short8*)&V_lds[srow * 64 + dcB] = vr1;
        if (kt + 1 < span) {      // prefetch kt+1: stays in flight across barrier
            kr0 = *(const short8*)(kb + (size_t)((kt + 1) * 64 + srow) * 64 + c0 * 8);
            kr1 = *(const short8*)(kb + (size_t)((kt + 1) * 64 + srow) * 64 + (c0 + 4) * 8);
            vr0 = *(const short8*)(vb + (size_t)srow * SEQ + (kt + 1) * 64 + c0 * 8);
            vr1 = *(const short8*)(vb + (size_t)srow * SEQ + (kt + 1) * 64 + (c0 + 4) * 8);
        }
        asm volatile("s_waitcnt lgkmcnt(0)" ::: "memory");  // my ds_writes done
        __builtin_amdgcn_s_barrier();                       // no vmcnt(0) drain
        asm volatile("" ::: "memory");

        // QK^T + exp2 + pack fused per nb: scores die into pf immediately.
        short4_ pf0[4], pf1[4];
#pragma unroll
        for (int nb = 0; nb < 4; nb++) {
            short8 k0 = *(const short8*)&K_lds[(nb * 16 + l15) * 64 + ((quad ^ l7) << 3)];
            short8 k1 = *(const short8*)&K_lds[(nb * 16 + l15) * 64 + (((quad + 4) ^ l7) << 3)];
            float4_ a = {0.f, 0.f, 0.f, 0.f};
            a = MFMA16(k0, qA0, a);
            a = MFMA16(k1, qA1, a);
            float4_ b = {0.f, 0.f, 0.f, 0.f};
            b = MFMA16(k0, qB0, b);
            b = MFMA16(k1, qB1, b);

            float p00 = EXP2(a[0]), p01 = EXP2(a[1]);
            float p02 = EXP2(a[2]), p03 = EXP2(a[3]);
            li0 += (p00 + p01) + (p02 + p03);
            float p10 = EXP2(b[0]), p11 = EXP2(b[1]);
            float p12 = EXP2(b[2]), p13 = EXP2(b[3]);
            li1 += (p10 + p11) + (p12 + p13);
            union { short4_ s; uint32_t u[2]; } pa, pb;
            asm("v_cvt_pk_bf16_f32 %0, %1, %2" : "=v"(pa.u[0]) : "v"(p00), "v"(p01));
            asm("v_cvt_pk_bf16_f32 %0, %1, %2" : "=v"(pa.u[1]) : "v"(p02), "v"(p03));
            asm("v_cvt_pk_bf16_f32 %0, %1, %2" : "=v"(pb.u[0]) : "v"(p10), "v"(p11));
            asm("v_cvt_pk_bf16_f32 %0, %1, %2" : "=v"(pb.u[1]) : "v"(p12), "v"(p13));
            pf0[nb] = pa.s;
            pf1[nb] = pb.s;
        }

        __builtin_amdgcn_s_setprio(1);
#pragma unroll
        for (int md = 0; md < 4; md++)
#pragma unroll
            for (int nb = 0; nb < 4; nb++) {
                int c = nb * 2 + (quad >> 1);
                short4_ vf = *(const short4_*)&V_lds[(md * 16 + l15) * 64 +
                                                     ((c ^ l7) << 3) + ((quad & 1) << 2)];
                oacc0[md] = MFMA16K16(vf, pf0[nb], oacc0[md]);
                oacc1[md] = MFMA16K16(vf, pf1[nb], oacc1[md]);
            }
        __builtin_amdgcn_s_setprio(0);
    }

    li0 += __shfl_xor(li0, 16);
    li0 += __shfl_xor(li0, 32);
    li1 += __shfl_xor(li1, 16);
    li1 += __shfl_xor(li1, 32);

    short* Op = grp ? O1 : O0;
    float* lp = grp ? l1 : l0;
    if (quad == 0) {
        lp[bh * 4096 + qrow0] = li0;
        lp[bh * 4096 + qrow1] = li1;
    }

    size_t ob0 = ((size_t)bh * 4096 + qrow0) * 64;
    size_t ob1 = ((size_t)bh * 4096 + qrow1) * 64;
#pragma unroll
    for (int md = 0; md < 4; md++) {
        short4_ pk0, pk1;
#pragma unroll
        for (int r = 0; r < 4; r++) {
            pk0[r] = f2bs(oacc0[md][r]);
            pk1[r] = f2bs(oacc1[md][r]);
        }
        *(short4_*)(Op + ob0 + md * 16 + quad * 4) = pk0;
        *(short4_*)(Op + ob1 + md * 16 + quad * 4) = pk1;
    }
}

// --------------------------------------------------------------- combine ----
// Fallback path only (small ws): out = (O0 [+ O1]) / (l0 [+ l1]).
__global__ __launch_bounds__(256) void combine_kernel(
    const short* O0, const short* O1, const float* l0, const float* l1,
    short* Oout, int two)
{
    int g = blockIdx.x * 256 + threadIdx.x;     // short4 units, 1048576 total
    int qi = g >> 4;
    short4_ a = *(const short4_*)(O0 + (size_t)g * 4);
    float l = l0[qi];
    float4_ acc = {s2f(a[0]), s2f(a[1]), s2f(a[2]), s2f(a[3])};
    if (two) {
        short4_ b = *(const short4_*)(O1 + (size_t)g * 4);
        l += l1[qi];
#pragma unroll
        for (int j = 0; j < 4; j++) acc[j] += s2f(b[j]);
    }
    float inv = 1.f / l;
    short4_ pk;
#pragma unroll
    for (int j = 0; j < 4; j++) pk[j] = f2bs(acc[j] * inv);
    *(short4_*)(Oout + (size_t)g * 4) = pk;
}

// ------------------------------------------------------------------- mlp ----
// Fused back half: (O@woT + bo + xt) -> av -> LN2 -> xn2 -> (@w1T + b1) ->
// GELU -> ff -> (@w2T + b2 + av) -> fp32 transpose-store to [b][c][sp].
// v2: combine folded into stage A. If two==2, the A-fragment is built as
// cvt_pk((s2f(O0)+s2f(O1)) * 1/(l0+l1)) — bit-identical rounding to the old
// combine kernel (both RNE once from the same fp32 value). 1/l is per
// (head, token): 4 loop-invariant scalars per lane. If two==0, O0 is already
// normalized (fallback path) and is used directly.
__global__ __launch_bounds__(256) void mlp_kernel(
    const short* O0, const short* O1, const float* l0, const float* l1, int two,
    const short* woT, const short* w1T, const short* w2T,
    const float* bo, const float* b1, const float* b2,
    const float* g2, const float* be2,
    const short* xt, float* outf)
{
    __shared__ __align__(16) char smem[3 * 8448 + 128];
    short* av = (short*)smem;                   // [16][264] bf16
    short* x2 = (short*)(smem + 8448);          // [16][264] bf16
    short* ff = (short*)(smem + 16896);         // [16][264] bf16
    float* stats = (float*)(smem + 25344);      // mu[16], rs[16]
    float* T = (float*)smem;                    // alias av|x2 (16.6 KB <= 16.9)

    int tid = threadIdx.x;
    int w = tid >> 6, lane = tid & 63, quad = lane >> 4, l15 = lane & 15;
    int m0 = blockIdx.x * 16;
    int n0 = w * 64;
    int arow = m0 + l15;
    int bbA = arow >> 12, spA = arow & 4095;

    // per-(head,token) normalizers (loop-invariant, small cached loads)
    float invh[4];
    if (two) {
#pragma unroll
        for (int h = 0; h < 4; h++) {
            size_t li = (size_t)(bbA * 4 + h) * 4096 + spA;
            invh[h] = 1.f / (l0[li] + l1[li]);
        }
    }

    // ---- stage A: attention out-proj + xt residual -> av (LDS bf16) ----
    float4_ acc[4];
#pragma unroll
    for (int nb = 0; nb < 4; nb++) {
        float bvv = bo[n0 + nb * 16 + l15];
        acc[nb] = {bvv, bvv, bvv, bvv};
    }
    for (int kc = 0; kc < 8; kc++) {
        int h = kc >> 1;
        int off = (kc & 1) * 32 + quad * 8;
        size_t obase = ((size_t)(bbA * 4 + h) * 4096 + spA) * 64 + off;
        short8 a;
        if (two) {
            short8 a0v = *(const short8*)(O0 + obase);
            short8 a1v = *(const short8*)(O1 + obase);
            float iv = invh[h];
            union { short8 s; uint32_t u[4]; } pa;
#pragma unroll
            for (int jj = 0; jj < 4; jj++) {
                float f0 = (s2f(a0v[2 * jj]) + s2f(a1v[2 * jj])) * iv;
                float f1 = (s2f(a0v[2 * jj + 1]) + s2f(a1v[2 * jj + 1])) * iv;
                asm("v_cvt_pk_bf16_f32 %0, %1, %2" : "=v"(pa.u[jj]) : "v"(f0), "v"(f1));
            }
            a = pa.s;
        } else {
            a = *(const short8*)(O0 + obase);
        }
#pragma unroll
        for (int nb = 0; nb < 4; nb++) {
            short8 b = *(const short8*)(woT + (size_t)(n0 + nb * 16 + l15) * 256 + kc * 32 + quad * 8);
            acc[nb] = MFMA16(a, b, acc[nb]);
        }
    }
#pragma unroll
    for (int nb = 0; nb < 4; nb++) {
        int col = n0 + nb * 16 + l15;
#pragma unroll
        for (int r = 0; r < 4; r++) {
            size_t t = (size_t)m0 + quad * 4 + r;
            av[(quad * 4 + r) * 264 + col] = f2bs(acc[nb][r] + s2f(xt[t * 256 + col]));
        }
    }
    __syncthreads();

    // ---- stage B: LN2 stats (16 threads per row, each sums 16 cols) ----
    {
        int row = tid >> 4, sub = tid & 15;
        float sum = 0.f, ss = 0.f;
        short8 v0 = *(const short8*)&av[row * 264 + sub * 16];
        short8 v1 = *(const short8*)&av[row * 264 + sub * 16 + 8];
#pragma unroll
        for (int j = 0; j < 8; j++) {
            float a = s2f(v0[j]), b = s2f(v1[j]);
            sum += a + b; ss += a * a + b * b;
        }
#pragma unroll
        for (int off = 1; off < 16; off <<= 1) {
            sum += __shfl_xor(sum, off);
            ss += __shfl_xor(ss, off);
        }
        if (sub == 0) {
            float mu = sum * (1.f / 256.f);
            float var = ss * (1.f / 256.f) - mu * mu;
            stats[row] = mu;
            stats[16 + row] = rsqrtf(var + 1e-5f);
        }
    }
    __syncthreads();

    // ---- stage C: xn2 = (av - mu) * rs * g2 + be2 (LDS bf16) ----
    {
        int row = tid >> 4, sub = tid & 15;
        float mu = stats[row], rs = stats[16 + row];
#pragma unroll
        for (int j = 0; j < 16; j += 4) {
            int c = sub * 16 + j;
            short4_ rv = *(const short4_*)&av[row * 264 + c];
            short4_ pk;
#pragma unroll
            for (int i = 0; i < 4; i++)
                pk[i] = f2bs((s2f(rv[i]) - mu) * rs * g2[c + i] + be2[c + i]);
            *(short4_*)&x2[row * 264 + c] = pk;
        }
    }
    __syncthreads();

    // ---- stage D: gemm1 + exact GELU -> ff (LDS bf16) ----
#pragma unroll
    for (int nb = 0; nb < 4; nb++) {
        float bvv = b1[n0 + nb * 16 + l15];
        acc[nb] = {bvv, bvv, bvv, bvv};
    }
    for (int kc = 0; kc < 8; kc++) {
        short8 a = *(const short8*)&x2[l15 * 264 + kc * 32 + quad * 8];
#pragma unroll
        for (int nb = 0; nb < 4; nb++) {
            short8 b = *(const short8*)(w1T + (size_t)(n0 + nb * 16 + l15) * 256 + kc * 32 + quad * 8);
            acc[nb] = MFMA16(a, b, acc[nb]);
        }
    }
#pragma unroll
    for (int nb = 0; nb < 4; nb++) {
        int col = n0 + nb * 16 + l15;
#pragma unroll
        for (int r = 0; r < 4; r++) {
            float v = acc[nb][r];
            v = 0.5f * v * (1.f + erff(v * 0.70710678118f));
            ff[(quad * 4 + r) * 264 + col] = f2bs(v);
        }
    }
    __syncthreads();

    // ---- stage E: gemm2 + av residual ----
#pragma unroll
    for (int nb = 0; nb < 4; nb++) {
        float bvv = b2[n0 + nb * 16 + l15];
        acc[nb] = {bvv, bvv, bvv, bvv};
    }
    for (int kc = 0; kc < 8; kc++) {
        short8 a = *(const short8*)&ff[l15 * 264 + kc * 32 + quad * 8];
#pragma unroll
        for (int nb = 0; nb < 4; nb++) {
            short8 b = *(const short8*)(w2T + (size_t)(n0 + nb * 16 + l15) * 256 + kc * 32 + quad * 8);
            acc[nb] = MFMA16(a, b, acc[nb]);
        }
    }
    float vout[4][4];
#pragma unroll
    for (int nb = 0; nb < 4; nb++) {
        int col = n0 + nb * 16 + l15;
#pragma unroll
        for (int r = 0; r < 4; r++)
            vout[nb][r] = acc[nb][r] + s2f(av[(quad * 4 + r) * 264 + col]);
    }
    __syncthreads();   // all reads of av/x2/ff complete before T alias writes

    // wave-private fp32 transpose -> coalesced [b][c][sp] stores
    float* tw = T + w * 1040;
#pragma unroll
    for (int nb = 0; nb < 4; nb++)
#pragma unroll
        for (int r = 0; r < 4; r++)
            tw[(quad * 4 + r) * 65 + nb * 16 + l15] = vout[nb][r];

    int bb = m0 >> 12;
    int spb = m0 & 4095;
    float* dst = outf + ((size_t)bb * 256 + n0 + lane) * SEQ + spb;
#pragma unroll
    for (int j = 0; j < 16; j += 4) {
        float4_ pk = {tw[(j + 0) * 65 + lane], tw[(j + 1) * 65 + lane],
                      tw[(j + 2) * 65 + lane], tw[(j + 3) * 65 + lane]};
        *(float4_*)(dst + j) = pk;
    }
}

// ---------------------------------------------------------------- launch ----
// Fused path (ws >= ~41.5 MB): O0 AND O1 both live in ws, so mlp reads only
// ws and can write all 16 MB of d_out; combine_kernel is not launched (its
// normalize is folded into mlp stage A). Fallback: previous split/combine
// layout, unchanged.
extern "C" void kernel_launch(void* const* d_in, const int* in_sizes, int n_in,
                              void* d_out, int out_size, void* d_ws, size_t ws_size,
                              hipStream_t stream)
{
    const float* x     = (const float*)d_in[0];
    const float* ln1_g = (const float*)d_in[1];
    const float* ln1_b = (const float*)d_in[2];
    const float* wq    = (const float*)d_in[3];
    const float* bq    = (const float*)d_in[4];
    const float* wk    = (const float*)d_in[5];
    const float* bk    = (const float*)d_in[6];
    const float* wv    = (const float*)d_in[7];
    const float* bv    = (const float*)d_in[8];
    const float* wo    = (const float*)d_in[9];
    const float* bo    = (const float*)d_in[10];
    const float* ln2_g = (const float*)d_in[11];
    const float* ln2_b = (const float*)d_in[12];
    const float* w1    = (const float*)d_in[13];
    const float* b1    = (const float*)d_in[14];
    const float* w2    = (const float*)d_in[15];
    const float* b2    = (const float*)d_in[16];

    char* ws = (char*)d_ws;
    const size_t SZ_BF = (size_t)TOK * 256 * 2;  // 8 MB

    short* wqT = (short*)(ws + 0);
    short* wkT = (short*)(ws + 8192);
    short* wvT = (short*)(ws + 16384);
    short* woT = (short*)(ws + 24576);
    short* w1T = (short*)(ws + 155648);
    short* w2T = (short*)(ws + 286720);
    char* base = ws + 524288;

    short* xt  = (short*)(base);
    short* kbuf= (short*)(base + SZ_BF);
    short* vtb = (short*)(base + 2 * SZ_BF);
    float* l0  = (float*)(base + 3 * SZ_BF);             // 256 KB
    float* l1  = (float*)(base + 3 * SZ_BF + 262144);    // 256 KB
    short* O1  = (short*)(base + 3 * SZ_BF + 524288);    // 8 MB (split only)
    short* O0w = (short*)(base + 4 * SZ_BF + 524288);    // 8 MB (fused only)

    const size_t NEED_SPLIT = 524288 + 3 * SZ_BF + 524288 + SZ_BF;
    const size_t NEED_FUSED = 524288 + 5 * SZ_BF + 524288;
    int nz = (ws_size >= NEED_SPLIT) ? 2 : 1;
    int fuse = (nz == 2 && ws_size >= NEED_FUSED);

    short* qb  = (short*)d_out;                      // lower 8 MB
    short* xn  = (short*)((char*)d_out + SZ_BF);     // upper 8 MB
    short* O0  = fuse ? O0w : xn;                    // partial O
    short* Onrm= vtb;                                // normalized O (fallback)

    repack_kernel<<<816, 256, 0, stream>>>(wq, wk, wv, wo, w1, w2,
                                           wqT, wkT, wvT, woT, w1T, w2T);
    ln1_kernel<<<TOK / 64, 64, 0, stream>>>(x, ln1_g, ln1_b, xn, xt);
    qkv_kernel<<<TOK / 64, 256, 0, stream>>>(xn, wqT, wkT, wvT, bq, bk, bv,
                                             qb, kbuf, vtb);
    flash_kernel<<<dim3(32, 16, nz), 256, 0, stream>>>(qb, kbuf, vtb, O0, O1, l0, l1);
    if (fuse) {
        mlp_kernel<<<TOK / 16, 256, 0, stream>>>(O0, O1, l0, l1, 2,
                                                 woT, w1T, w2T, bo, b1, b2,
                                                 ln2_g, ln2_b, xt, (float*)d_out);
    } else {
        combine_kernel<<<4096, 256, 0, stream>>>(O0, O1, l0, l1, Onrm, nz - 1);
        mlp_kernel<<<TOK / 16, 256, 0, stream>>>(Onrm, O1, l0, l1, 0,
                                                 woT, w1T, w2T, bo, b1, b2,
                                                 ln2_g, ln2_b, xt, (float*)d_out);
    }
}

// Round 3
// 271.496 us; speedup vs baseline: 1.0680x; 1.0323x over previous
//
#include <hip/hip_runtime.h>
#include <hip/hip_bf16.h>
#include <cstdint>

typedef __attribute__((ext_vector_type(8))) short short8;
typedef __attribute__((ext_vector_type(4))) short short4_;
typedef __attribute__((ext_vector_type(4))) float float4_;

#define MFMA16(a,b,c)  __builtin_amdgcn_mfma_f32_16x16x32_bf16(a,b,c,0,0,0)
#define MFMA16K16(a,b,c) __builtin_amdgcn_mfma_f32_16x16x16bf16_1k(a,b,c,0,0,0)
#define EXP2(x) __builtin_amdgcn_exp2f(x)

// fast bf16 RNE: bit-identical to __float2bfloat16 for all non-NaN inputs.
__device__ __forceinline__ short f2bs(float f) {
    union { float f; uint32_t u; } c;
    c.f = f;
    c.u += 0x7FFF + ((c.u >> 16) & 1);
    return (short)(c.u >> 16);
}
__device__ __forceinline__ float s2f(short s) {
    union { uint32_t u; float f; } c;
    c.u = ((uint32_t)(uint16_t)s) << 16;
    return c.f;
}

static const int EMB = 256;
static const int SEQ = 4096;   // 64*64 spatial
static const int TOK = 16384;  // BS * SEQ

static const size_t SZO = 4194304;   // shorts per O-partial (8 MB)
static const size_t LSTRIDE = 65536; // floats per l-partial (256 KB)

// Attention scale folded into wq/bq: (1/8) * log2(e) -> softmax in exp2 domain.
#define QSCALE 0.18033688011112042f

// ---------------------------------------------------------------- repack ----
__global__ __launch_bounds__(256) void repack_kernel(
    const float* wq, const float* wk, const float* wv,
    const float* wo, const float* w1, const float* w2,
    short* wqT, short* wkT, short* wvT, short* woT, short* w1T, short* w2T)
{
    int idx = blockIdx.x * 256 + threadIdx.x;
    if (idx < 3 * 4096) {
        int m = idx / 4096, r = idx % 4096;
        int n = r / 64, k = r % 64;
        const float* src = (m == 0) ? wq : (m == 1) ? wk : wv;
        short* dst = (m == 0) ? wqT : (m == 1) ? wkT : wvT;
        float v = src[k * 64 + n];
        if (m == 0) v *= QSCALE;
        dst[n * 64 + k] = f2bs(v);
    } else {
        int idx2 = idx - 3 * 4096;
        if (idx2 < 3 * 65536) {
            int m = idx2 / 65536, r = idx2 % 65536;
            int n = r / 256, k = r % 256;
            const float* src = (m == 0) ? wo : (m == 1) ? w1 : w2;
            short* dst = (m == 0) ? woT : (m == 1) ? w1T : w2T;
            dst[n * 256 + k] = f2bs(src[k * 256 + n]);
        }
    }
}

// ------------------------------------------------------------------- ln1 ----
// v2: occupancy fix. Old: 64-thr blocks, 1 thread/token = 1 wave/CU (~3%
// occupancy), two strided passes over x. New: 256-thr block = 32 tokens x
// 8 channel-parts; each thread holds its 32 channel values in REGISTERS
// (single pass), stats via shfl(32) pair-reduce + LDS cross-wave reduce.
// 512 blocks -> 8 waves/CU.
__global__ __launch_bounds__(256) void ln1_kernel(
    const float* x, const float* g, const float* bta,
    short* xn, short* xt)
{
    __shared__ float redS[4][32], redQ[4][32];
    int tid = threadIdx.x;
    int l = tid & 31;          // token lane
    int p = tid >> 5;          // channel part 0..7 (32 channels each)
    int t = blockIdx.x * 32 + l;
    int b = t >> 12, sp = t & 4095;
    const float* xb = x + (size_t)b * EMB * SEQ + (size_t)(p * 32) * SEQ + sp;

    float v[32];
    float sum = 0.f, ss = 0.f;
#pragma unroll
    for (int j = 0; j < 32; j++) {
        v[j] = xb[(size_t)j * SEQ];
        sum += v[j]; ss += v[j] * v[j];
    }
    // parts 2k/2k+1 live in the two halves of one wave
    sum += __shfl_xor(sum, 32);
    ss  += __shfl_xor(ss, 32);
    int w = tid >> 6;
    if ((tid & 32) == 0) { redS[w][l] = sum; redQ[w][l] = ss; }
    __syncthreads();
    float S = (redS[0][l] + redS[1][l]) + (redS[2][l] + redS[3][l]);
    float Q = (redQ[0][l] + redQ[1][l]) + (redQ[2][l] + redQ[3][l]);
    float mu = S * (1.f / 256.f);
    float var = Q * (1.f / 256.f) - mu * mu;
    float rs = rsqrtf(var + 1e-5f);

    short* xnr = xn + (size_t)t * 256 + p * 32;
    short* xtr = xt + (size_t)t * 256 + p * 32;
#pragma unroll
    for (int c = 0; c < 32; c += 8) {
        short8 ra, na;
#pragma unroll
        for (int j = 0; j < 8; j++) {
            float vv = v[c + j];
            ra[j] = f2bs(vv);
            na[j] = f2bs((vv - mu) * rs * g[p * 32 + c + j] + bta[p * 32 + c + j]);
        }
        *(short8*)(xtr + c) = ra;
        *(short8*)(xnr + c) = na;
    }
}

// ------------------------------------------------------------------- qkv ----
// (verbatim — passing)
__global__ __launch_bounds__(256) void qkv_kernel(
    const short* xn, const short* wqT, const short* wkT, const short* wvT,
    const float* bq, const float* bk, const float* bv,
    short* qo, short* ko, short* vto)
{
    int tid = threadIdx.x;
    int w = tid >> 6, lane = tid & 63, quad = lane >> 4, l15 = lane & 15;
    int m0 = blockIdx.x * 64 + w * 16;
    int row = m0 + l15;
    int bb = row >> 12;
    int s0 = (m0 & 4095) + quad * 4;

    short8 a0[4], a1[4];
#pragma unroll
    for (int h = 0; h < 4; h++) {
        a0[h] = *(const short8*)(xn + (size_t)row * 256 + h * 64 + quad * 8);
        a1[h] = *(const short8*)(xn + (size_t)row * 256 + h * 64 + 32 + quad * 8);
    }

#pragma unroll
    for (int p = 0; p < 3; p++) {
        const short* WT = (p == 0) ? wqT : (p == 1) ? wkT : wvT;
        const float* bias = (p == 0) ? bq : (p == 1) ? bk : bv;
        float bscale = (p == 0) ? QSCALE : 1.f;
#pragma unroll
        for (int nb = 0; nb < 4; nb++) {
            int col = nb * 16 + l15;
            short8 b0 = *(const short8*)(WT + col * 64 + quad * 8);
            short8 b1 = *(const short8*)(WT + col * 64 + 32 + quad * 8);
            float bvv = bias[col] * bscale;
#pragma unroll
            for (int h = 0; h < 4; h++) {
                float4_ acc = {bvv, bvv, bvv, bvv};
                acc = MFMA16(a0[h], b0, acc);
                acc = MFMA16(a1[h], b1, acc);
                size_t headbase = (size_t)(bb * 4 + h) * SEQ;
                if (p < 2) {
                    short* dst = (p == 0) ? qo : ko;
#pragma unroll
                    for (int r = 0; r < 4; r++)
                        dst[(headbase + s0 + r) * 64 + col] = f2bs(acc[r]);
                } else {
                    short4_ pk;
#pragma unroll
                    for (int r = 0; r < 4; r++) pk[r] = f2bs(acc[r]);
                    *(short4_*)(vto + ((size_t)(bb * 4 + h) * 64 + col) * SEQ + s0) = pk;
                }
            }
        }
    }
}

// ----------------------------------------------------------------- flash ----
// v10: v9 + occupancy. Grid z (nz) now up to 4 -> 2048 blocks = 8 blocks/CU
// (LDS 8x16KB=128<=160KB, VGPR 64 -> 8 waves/SIMD allowed). Total LDS traffic
// is invariant in nz (blocks x kt constant), unlike a Q-split. Partial O for
// grp>=1 lives at Orest + (grp-1)*SZO; l at lbase + grp*LSTRIDE.
__global__ __attribute__((amdgpu_flat_work_group_size(256, 256),
                          amdgpu_waves_per_eu(4, 8)))
void flash_kernel(
    const short* q, const short* k, const short* vt,
    short* O0, short* Orest, float* lbase)
{
    __shared__ short K_lds[64 * 64];
    __shared__ short V_lds[64 * 64];

    int tid = threadIdx.x;
    int w = tid >> 6, lane = tid & 63, quad = lane >> 4, l15 = lane & 15;
    int qt = blockIdx.x, bh = blockIdx.y, grp = blockIdx.z;
    int span = 64 / gridDim.z;              // K-tiles per block

    const short* qb = q + (size_t)bh * SEQ * 64;
    const short* kb = k + (size_t)bh * SEQ * 64 + (size_t)grp * span * 64 * 64;
    const short* vb = vt + (size_t)bh * 64 * SEQ + grp * span * 64;

    int qrow0 = qt * 128 + w * 32 + l15;
    int qrow1 = qrow0 + 16;
    short8 qA0 = *(const short8*)(qb + (size_t)qrow0 * 64 + quad * 8);
    short8 qA1 = *(const short8*)(qb + (size_t)qrow0 * 64 + 32 + quad * 8);
    short8 qB0 = *(const short8*)(qb + (size_t)qrow1 * 64 + quad * 8);
    short8 qB1 = *(const short8*)(qb + (size_t)qrow1 * 64 + 32 + quad * 8);

    float4_ oacc0[4], oacc1[4];   // O^T[d = md*16 + quad*4 + r][query = l15]
#pragma unroll
    for (int md = 0; md < 4; md++) {
        oacc0[md] = {0.f, 0.f, 0.f, 0.f};
        oacc1[md] = {0.f, 0.f, 0.f, 0.f};
    }
    float li0 = 0.f, li1 = 0.f;

    int srow = tid >> 2;          // 0..63
    int sr7 = srow & 7;
    int c0 = tid & 3;             // chunk (16B units)
    int l7 = l15 & 7;

    int dcA = (c0 ^ sr7) << 3;
    int dcB = ((c0 + 4) ^ sr7) << 3;

    // prologue: stage tile 0 into registers
    short8 kr0 = *(const short8*)(kb + (size_t)srow * 64 + c0 * 8);
    short8 kr1 = *(const short8*)(kb + (size_t)srow * 64 + (c0 + 4) * 8);
    short8 vr0 = *(const short8*)(vb + (size_t)srow * SEQ + c0 * 8);
    short8 vr1 = *(const short8*)(vb + (size_t)srow * SEQ + (c0 + 4) * 8);

    for (int kt = 0; kt < span; kt++) {
        __syncthreads();          // prev-tile LDS reads done; vmcnt drain ~free
        *(short8*)&K_lds[srow * 64 + dcA] = kr0;
        *(short8*)&K_lds[srow * 64 + dcB] = kr1;
        *(short8*)&V_lds[srow * 64 + dcA] = vr0;
        *(short8*)&V_lds[srow * 64 + dcB] = vr1;
        if (kt + 1 < span) {      // prefetch kt+1: stays in flight across barrier
            kr0 = *(const short8*)(kb + (size_t)((kt + 1) * 64 + srow) * 64 + c0 * 8);
            kr1 = *(const short8*)(kb + (size_t)((kt + 1) * 64 + srow) * 64 + (c0 + 4) * 8);
            vr0 = *(const short8*)(vb + (size_t)srow * SEQ + (kt + 1) * 64 + c0 * 8);
            vr1 = *(const short8*)(vb + (size_t)srow * SEQ + (kt + 1) * 64 + (c0 + 4) * 8);
        }
        asm volatile("s_waitcnt lgkmcnt(0)" ::: "memory");  // my ds_writes done
        __builtin_amdgcn_s_barrier();                       // no vmcnt(0) drain
        asm volatile("" ::: "memory");

        // QK^T + exp2 + pack fused per nb: scores die into pf immediately.
        short4_ pf0[4], pf1[4];
#pragma unroll
        for (int nb = 0; nb < 4; nb++) {
            short8 k0 = *(const short8*)&K_lds[(nb * 16 + l15) * 64 + ((quad ^ l7) << 3)];
            short8 k1 = *(const short8*)&K_lds[(nb * 16 + l15) * 64 + (((quad + 4) ^ l7) << 3)];
            float4_ a = {0.f, 0.f, 0.f, 0.f};
            a = MFMA16(k0, qA0, a);
            a = MFMA16(k1, qA1, a);
            float4_ b = {0.f, 0.f, 0.f, 0.f};
            b = MFMA16(k0, qB0, b);
            b = MFMA16(k1, qB1, b);

            float p00 = EXP2(a[0]), p01 = EXP2(a[1]);
            float p02 = EXP2(a[2]), p03 = EXP2(a[3]);
            li0 += (p00 + p01) + (p02 + p03);
            float p10 = EXP2(b[0]), p11 = EXP2(b[1]);
            float p12 = EXP2(b[2]), p13 = EXP2(b[3]);
            li1 += (p10 + p11) + (p12 + p13);
            union { short4_ s; uint32_t u[2]; } pa, pb;
            asm("v_cvt_pk_bf16_f32 %0, %1, %2" : "=v"(pa.u[0]) : "v"(p00), "v"(p01));
            asm("v_cvt_pk_bf16_f32 %0, %1, %2" : "=v"(pa.u[1]) : "v"(p02), "v"(p03));
            asm("v_cvt_pk_bf16_f32 %0, %1, %2" : "=v"(pb.u[0]) : "v"(p10), "v"(p11));
            asm("v_cvt_pk_bf16_f32 %0, %1, %2" : "=v"(pb.u[1]) : "v"(p12), "v"(p13));
            pf0[nb] = pa.s;
            pf1[nb] = pb.s;
        }

        __builtin_amdgcn_s_setprio(1);
#pragma unroll
        for (int md = 0; md < 4; md++)
#pragma unroll
            for (int nb = 0; nb < 4; nb++) {
                int c = nb * 2 + (quad >> 1);
                short4_ vf = *(const short4_*)&V_lds[(md * 16 + l15) * 64 +
                                                     ((c ^ l7) << 3) + ((quad & 1) << 2)];
                oacc0[md] = MFMA16K16(vf, pf0[nb], oacc0[md]);
                oacc1[md] = MFMA16K16(vf, pf1[nb], oacc1[md]);
            }
        __builtin_amdgcn_s_setprio(0);
    }

    li0 += __shfl_xor(li0, 16);
    li0 += __shfl_xor(li0, 32);
    li1 += __shfl_xor(li1, 16);
    li1 += __shfl_xor(li1, 32);

    short* Op = grp ? (Orest + (size_t)(grp - 1) * SZO) : O0;
    float* lp = lbase + (size_t)grp * LSTRIDE;
    if (quad == 0) {
        lp[bh * 4096 + qrow0] = li0;
        lp[bh * 4096 + qrow1] = li1;
    }

    size_t ob0 = ((size_t)bh * 4096 + qrow0) * 64;
    size_t ob1 = ((size_t)bh * 4096 + qrow1) * 64;
#pragma unroll
    for (int md = 0; md < 4; md++) {
        short4_ pk0, pk1;
#pragma unroll
        for (int r = 0; r < 4; r++) {
            pk0[r] = f2bs(oacc0[md][r]);
            pk1[r] = f2bs(oacc1[md][r]);
        }
        *(short4_*)(Op + ob0 + md * 16 + quad * 4) = pk0;
        *(short4_*)(Op + ob1 + md * 16 + quad * 4) = pk1;
    }
}

// --------------------------------------------------------------- combine ----
// Fallback path only: out = (sum of np partials) / (sum of np l's).
__global__ __launch_bounds__(256) void combine_kernel(
    const short* O0, const short* Orest, const float* lb,
    short* Oout, int np)
{
    int g = blockIdx.x * 256 + threadIdx.x;     // short4 units, 1048576 total
    int qi = g >> 4;
    short4_ a = *(const short4_*)(O0 + (size_t)g * 4);
    float l = lb[qi];
    float4_ acc = {s2f(a[0]), s2f(a[1]), s2f(a[2]), s2f(a[3])};
    for (int j = 1; j < np; j++) {
        short4_ b = *(const short4_*)(Orest + (size_t)(j - 1) * SZO + (size_t)g * 4);
        l += lb[(size_t)j * LSTRIDE + qi];
#pragma unroll
        for (int jj = 0; jj < 4; jj++) acc[jj] += s2f(b[jj]);
    }
    float inv = 1.f / l;
    short4_ pk;
#pragma unroll
    for (int j = 0; j < 4; j++) pk[j] = f2bs(acc[j] * inv);
    *(short4_*)(Oout + (size_t)g * 4) = pk;
}

// ------------------------------------------------------------------- mlp ----
// Fused back half: (O@woT + bo + xt) -> av -> LN2 -> xn2 -> (@w1T + b1) ->
// GELU -> ff -> (@w2T + b2 + av) -> fp32 transpose-store to [b][c][sp].
// v3: combine folded into stage A for np partials (np=0: O0 pre-normalized).
// A-fragment = cvt_pk((sum of partials) * 1/(sum of l)) — bit-identical
// rounding to the standalone combine kernel.
__global__ __launch_bounds__(256) void mlp_kernel(
    const short* O0, const short* Orest, const float* lb, int np,
    const short* woT, const short* w1T, const short* w2T,
    const float* bo, const float* b1, const float* b2,
    const float* g2, const float* be2,
    const short* xt, float* outf)
{
    __shared__ __align__(16) char smem[3 * 8448 + 128];
    short* av = (short*)smem;                   // [16][264] bf16
    short* x2 = (short*)(smem + 8448);          // [16][264] bf16
    short* ff = (short*)(smem + 16896);         // [16][264] bf16
    float* stats = (float*)(smem + 25344);      // mu[16], rs[16]
    float* T = (float*)smem;                    // alias av|x2 (16.6 KB <= 16.9)

    int tid = threadIdx.x;
    int w = tid >> 6, lane = tid & 63, quad = lane >> 4, l15 = lane & 15;
    int m0 = blockIdx.x * 16;
    int n0 = w * 64;
    int arow = m0 + l15;
    int bbA = arow >> 12, spA = arow & 4095;

    // per-(head,token) normalizers (loop-invariant, small cached loads)
    float invh[4];
    if (np) {
#pragma unroll
        for (int h = 0; h < 4; h++) {
            size_t li = (size_t)(bbA * 4 + h) * 4096 + spA;
            float s = lb[li];
            for (int j = 1; j < np; j++) s += lb[(size_t)j * LSTRIDE + li];
            invh[h] = 1.f / s;
        }
    }

    // ---- stage A: attention out-proj + xt residual -> av (LDS bf16) ----
    float4_ acc[4];
#pragma unroll
    for (int nb = 0; nb < 4; nb++) {
        float bvv = bo[n0 + nb * 16 + l15];
        acc[nb] = {bvv, bvv, bvv, bvv};
    }
    for (int kc = 0; kc < 8; kc++) {
        int h = kc >> 1;
        int off = (kc & 1) * 32 + quad * 8;
        size_t obase = ((size_t)(bbA * 4 + h) * 4096 + spA) * 64 + off;
        short8 a;
        if (np) {
            short8 a0v = *(const short8*)(O0 + obase);
            float f[8];
#pragma unroll
            for (int jj = 0; jj < 8; jj++) f[jj] = s2f(a0v[jj]);
            for (int j = 1; j < np; j++) {
                short8 apv = *(const short8*)(Orest + (size_t)(j - 1) * SZO + obase);
#pragma unroll
                for (int jj = 0; jj < 8; jj++) f[jj] += s2f(apv[jj]);
            }
            float iv = invh[h];
            union { short8 s; uint32_t u[4]; } pa;
#pragma unroll
            for (int jj = 0; jj < 4; jj++) {
                float f0 = f[2 * jj] * iv;
                float f1 = f[2 * jj + 1] * iv;
                asm("v_cvt_pk_bf16_f32 %0, %1, %2" : "=v"(pa.u[jj]) : "v"(f0), "v"(f1));
            }
            a = pa.s;
        } else {
            a = *(const short8*)(O0 + obase);
        }
#pragma unroll
        for (int nb = 0; nb < 4; nb++) {
            short8 b = *(const short8*)(woT + (size_t)(n0 + nb * 16 + l15) * 256 + kc * 32 + quad * 8);
            acc[nb] = MFMA16(a, b, acc[nb]);
        }
    }
#pragma unroll
    for (int nb = 0; nb < 4; nb++) {
        int col = n0 + nb * 16 + l15;
#pragma unroll
        for (int r = 0; r < 4; r++) {
            size_t t = (size_t)m0 + quad * 4 + r;
            av[(quad * 4 + r) * 264 + col] = f2bs(acc[nb][r] + s2f(xt[t * 256 + col]));
        }
    }
    __syncthreads();

    // ---- stage B: LN2 stats (16 threads per row, each sums 16 cols) ----
    {
        int row = tid >> 4, sub = tid & 15;
        float sum = 0.f, ss = 0.f;
        short8 v0 = *(const short8*)&av[row * 264 + sub * 16];
        short8 v1 = *(const short8*)&av[row * 264 + sub * 16 + 8];
#pragma unroll
        for (int j = 0; j < 8; j++) {
            float a = s2f(v0[j]), b = s2f(v1[j]);
            sum += a + b; ss += a * a + b * b;
        }
#pragma unroll
        for (int off = 1; off < 16; off <<= 1) {
            sum += __shfl_xor(sum, off);
            ss += __shfl_xor(ss, off);
        }
        if (sub == 0) {
            float mu = sum * (1.f / 256.f);
            float var = ss * (1.f / 256.f) - mu * mu;
            stats[row] = mu;
            stats[16 + row] = rsqrtf(var + 1e-5f);
        }
    }
    __syncthreads();

    // ---- stage C: xn2 = (av - mu) * rs * g2 + be2 (LDS bf16) ----
    {
        int row = tid >> 4, sub = tid & 15;
        float mu = stats[row], rs = stats[16 + row];
#pragma unroll
        for (int j = 0; j < 16; j += 4) {
            int c = sub * 16 + j;
            short4_ rv = *(const short4_*)&av[row * 264 + c];
            short4_ pk;
#pragma unroll
            for (int i = 0; i < 4; i++)
                pk[i] = f2bs((s2f(rv[i]) - mu) * rs * g2[c + i] + be2[c + i]);
            *(short4_*)&x2[row * 264 + c] = pk;
        }
    }
    __syncthreads();

    // ---- stage D: gemm1 + exact GELU -> ff (LDS bf16) ----
#pragma unroll
    for (int nb = 0; nb < 4; nb++) {
        float bvv = b1[n0 + nb * 16 + l15];
        acc[nb] = {bvv, bvv, bvv, bvv};
    }
    for (int kc = 0; kc < 8; kc++) {
        short8 a = *(const short8*)&x2[l15 * 264 + kc * 32 + quad * 8];
#pragma unroll
        for (int nb = 0; nb < 4; nb++) {
            short8 b = *(const short8*)(w1T + (size_t)(n0 + nb * 16 + l15) * 256 + kc * 32 + quad * 8);
            acc[nb] = MFMA16(a, b, acc[nb]);
        }
    }
#pragma unroll
    for (int nb = 0; nb < 4; nb++) {
        int col = n0 + nb * 16 + l15;
#pragma unroll
        for (int r = 0; r < 4; r++) {
            float v = acc[nb][r];
            v = 0.5f * v * (1.f + erff(v * 0.70710678118f));
            ff[(quad * 4 + r) * 264 + col] = f2bs(v);
        }
    }
    __syncthreads();

    // ---- stage E: gemm2 + av residual ----
#pragma unroll
    for (int nb = 0; nb < 4; nb++) {
        float bvv = b2[n0 + nb * 16 + l15];
        acc[nb] = {bvv, bvv, bvv, bvv};
    }
    for (int kc = 0; kc < 8; kc++) {
        short8 a = *(const short8*)&ff[l15 * 264 + kc * 32 + quad * 8];
#pragma unroll
        for (int nb = 0; nb < 4; nb++) {
            short8 b = *(const short8*)(w2T + (size_t)(n0 + nb * 16 + l15) * 256 + kc * 32 + quad * 8);
            acc[nb] = MFMA16(a, b, acc[nb]);
        }
    }
    float vout[4][4];
#pragma unroll
    for (int nb = 0; nb < 4; nb++) {
        int col = n0 + nb * 16 + l15;
#pragma unroll
        for (int r = 0; r < 4; r++)
            vout[nb][r] = acc[nb][r] + s2f(av[(quad * 4 + r) * 264 + col]);
    }
    __syncthreads();   // all reads of av/x2/ff complete before T alias writes

    // wave-private fp32 transpose -> coalesced [b][c][sp] stores
    float* tw = T + w * 1040;
#pragma unroll
    for (int nb = 0; nb < 4; nb++)
#pragma unroll
        for (int r = 0; r < 4; r++)
            tw[(quad * 4 + r) * 65 + nb * 16 + l15] = vout[nb][r];

    int bb = m0 >> 12;
    int spb = m0 & 4095;
    float* dst = outf + ((size_t)bb * 256 + n0 + lane) * SEQ + spb;
#pragma unroll
    for (int j = 0; j < 16; j += 4) {
        float4_ pk = {tw[(j + 0) * 65 + lane], tw[(j + 1) * 65 + lane],
                      tw[(j + 2) * 65 + lane], tw[(j + 3) * 65 + lane]};
        *(float4_*)(dst + j) = pk;
    }
}

// ---------------------------------------------------------------- launch ----
// ws tiers (proven available: >= 33.0 MB, the old nz=2 split layout):
//   nz=4 fused   (ws >= 57.5 MB): O0..O3 + l0..l3 in ws, mlp combines 4.
//   nz=4 split   (ws >= 49.5 MB): O0=d_out upper, O1..O3 in ws, combine(4).
//   nz=2 fused   (ws >= 41.0 MB): previous round's layout.
//   nz=2 split   (ws >= 33.0 MB): original proven layout.
//   nz=1         otherwise.
extern "C" void kernel_launch(void* const* d_in, const int* in_sizes, int n_in,
                              void* d_out, int out_size, void* d_ws, size_t ws_size,
                              hipStream_t stream)
{
    const float* x     = (const float*)d_in[0];
    const float* ln1_g = (const float*)d_in[1];
    const float* ln1_b = (const float*)d_in[2];
    const float* wq    = (const float*)d_in[3];
    const float* bq    = (const float*)d_in[4];
    const float* wk    = (const float*)d_in[5];
    const float* bk    = (const float*)d_in[6];
    const float* wv    = (const float*)d_in[7];
    const float* bv    = (const float*)d_in[8];
    const float* wo    = (const float*)d_in[9];
    const float* bo    = (const float*)d_in[10];
    const float* ln2_g = (const float*)d_in[11];
    const float* ln2_b = (const float*)d_in[12];
    const float* w1    = (const float*)d_in[13];
    const float* b1    = (const float*)d_in[14];
    const float* w2    = (const float*)d_in[15];
    const float* b2    = (const float*)d_in[16];

    char* ws = (char*)d_ws;
    const size_t SZ_BF = (size_t)TOK * 256 * 2;  // 8 MB

    short* wqT = (short*)(ws + 0);
    short* wkT = (short*)(ws + 8192);
    short* wvT = (short*)(ws + 16384);
    short* woT = (short*)(ws + 24576);
    short* w1T = (short*)(ws + 155648);
    short* w2T = (short*)(ws + 286720);
    char* base = ws + 524288;

    short* xt  = (short*)(base);
    short* kbuf= (short*)(base + SZ_BF);
    short* vtb = (short*)(base + 2 * SZ_BF);

    const size_t need2_fb = 524288 + 3 * SZ_BF + 524288 + SZ_BF;      // 33.0 MB
    const size_t need2_fu = need2_fb + SZ_BF;                          // 41.0 MB
    const size_t need4_fb = 524288 + 3 * SZ_BF + 1048576 + 3 * SZ_BF;  // 49.5 MB
    const size_t need4_fu = need4_fb + SZ_BF;                          // 57.5 MB

    int nz, fuse;
    if (ws_size >= need4_fb)      { nz = 4; fuse = (ws_size >= need4_fu); }
    else if (ws_size >= need2_fb) { nz = 2; fuse = (ws_size >= need2_fu); }
    else                          { nz = 1; fuse = 0; }

    float* lbase;
    short* Orest;
    short* O0w;
    if (nz == 4) {
        lbase = (float*)(base + 3 * SZ_BF);                 // 4 x 256 KB
        Orest = (short*)(base + 3 * SZ_BF + 1048576);       // O1..O3
        O0w   = Orest + 3 * SZO;                            // fused only
    } else {
        lbase = (float*)(base + 3 * SZ_BF);                 // 2 x 256 KB
        Orest = (short*)(base + 3 * SZ_BF + 524288);        // O1
        O0w   = Orest + SZO;                                // fused only
    }

    short* qb  = (short*)d_out;                      // lower 8 MB
    short* xn  = (short*)((char*)d_out + SZ_BF);     // upper 8 MB
    short* O0  = fuse ? O0w : xn;                    // partial O (grp 0)
    short* Onrm= vtb;                                // normalized O (fallback)

    repack_kernel<<<816, 256, 0, stream>>>(wq, wk, wv, wo, w1, w2,
                                           wqT, wkT, wvT, woT, w1T, w2T);
    ln1_kernel<<<TOK / 32, 256, 0, stream>>>(x, ln1_g, ln1_b, xn, xt);
    qkv_kernel<<<TOK / 64, 256, 0, stream>>>(xn, wqT, wkT, wvT, bq, bk, bv,
                                             qb, kbuf, vtb);
    flash_kernel<<<dim3(32, 16, nz), 256, 0, stream>>>(qb, kbuf, vtb, O0, Orest, lbase);
    if (fuse) {
        mlp_kernel<<<TOK / 16, 256, 0, stream>>>(O0, Orest, lbase, nz,
                                                 woT, w1T, w2T, bo, b1, b2,
                                                 ln2_g, ln2_b, xt, (float*)d_out);
    } else {
        combine_kernel<<<4096, 256, 0, stream>>>(O0, Orest, lbase, Onrm, nz);
        mlp_kernel<<<TOK / 16, 256, 0, stream>>>(Onrm, Orest, lbase, 0,
                                                 woT, w1T, w2T, bo, b1, b2,
                                                 ln2_g, ln2_b, xt, (float*)d_out);
    }
}